// Round 11
// baseline (133.988 us; speedup 1.0000x reference)
//
#include <hip/hip_runtime.h>
#include <math.h>

// Canny NMS mask, bit-exact vs the validated round-5 pipeline.
// v6: interior tiles use vector-LDS (b128 reads/writes, stride 76) and a
// fused sobel+mag+sector+NMS register phase (2 barriers, no mag LDS).
// Border tiles run the v5 scalar path verbatim. Per-pixel arithmetic
// chains are IDENTICAL to the validated pipeline on every path.

#define NT 256

__device__ __forceinline__ float grayf(float r, float g, float b) {
  return __fadd_rn(__fadd_rn(__fmul_rn(0.299f, r), __fmul_rn(0.587f, g)),
                   __fmul_rn(0.114f, b));
}

// sector classification: f32 slope test w/ guard band; in-band -> verbatim
// validated atan2f chain. (identical logic to v5)
__device__ __forceinline__ int sectorf(float gxf, float gyf) {
  const float Tnf = 0.41421356237309504880f;
  const float BETAf = 1e-4f;
  const float RAD2DEG = (float)(180.0 / 3.14159265358979323846);
  float uf = (gyf < 0.0f) ? -gxf : gxf;
  float vf = fabsf(gyf);
  float au = fabsf(uf);
  float p = au * Tnf, qq = vf * Tnf;
  int sec;
  if (uf > 0.0f)      sec = (vf < p) ? 0 : (uf > qq) ? 1 : 2;
  else if (uf < 0.0f) sec = (uf > -qq) ? 2 : (vf > p) ? 3 : 0;
  else                sec = (vf > 0.0f) ? 2 : 0;
  bool slow = (fabsf(vf - p) <= p * BETAf) || (fabsf(au - qq) <= qq * BETAf);
  if (slow) {
    float ang = __fmul_rn(atan2f(gyf, gxf), RAD2DEG);
    if (ang < 0.0f) ang = __fadd_rn(ang, 180.0f);
    sec = (ang < 22.5f) ? 0 : (ang < 67.5f) ? 1
        : (ang < 112.5f) ? 2 : (ang < 157.5f) ? 3 : 0;
  }
  return sec;
}

// ---------------- border path: v5 verbatim (scalar, masked) ----------------
__device__ __forceinline__ void canny_tile_border(
    const float* __restrict__ base, float* __restrict__ outp,
    int bx0, int by0, float* s_gray, float* s_blur, float* s_mag,
    unsigned char* s_sec, const double* w64, int tid) {
  const size_t plane = (size_t)512 * 512;

  for (int i = tid; i < 24 * 72; i += NT) {
    int ly = i / 72, lx = i - ly * 72;
    int gy = by0 - 4 + ly, gx = bx0 - 4 + lx;
    float val = 0.0f;
    if (gy >= 0 && gy < 512 && gx >= 0 && gx < 512) {
      size_t idx = (size_t)gy * 512 + gx;
      val = grayf(base[idx], base[idx + plane], base[idx + 2 * plane]);
    }
    s_gray[i] = val;
  }
  __syncthreads();

  auto blur_run = [&](int col, int q) {
    const int y0 = q * 5;
    const int ix = bx0 - 2 + col;
    const bool colok = (ix >= 0 && ix < 512);
    float win[5][5];
#pragma unroll
    for (int r = 0; r < 4; ++r)
#pragma unroll
      for (int c = 0; c < 5; ++c)
        win[r][c] = s_gray[(y0 + r) * 72 + col + c];
#pragma unroll
    for (int y = 0; y < 5; ++y) {
      const int pin = (y + 4) % 5;
#pragma unroll
      for (int c = 0; c < 5; ++c)
        win[pin][c] = s_gray[(y0 + y + 4) * 72 + col + c];
      double acc = 0.0;
#pragma unroll
      for (int r = 0; r < 5; ++r) {
        const int ph = (y + r) % 5;
#pragma unroll
        for (int c = 0; c < 5; ++c)
          acc = __builtin_fma(w64[r * 5 + c], (double)win[ph][c], acc);
      }
      int iy = by0 - 2 + y0 + y;
      s_blur[(y0 + y) * 68 + col] =
          (colok && iy >= 0 && iy < 512) ? (float)acc : 0.0f;
    }
  };
  blur_run(tid & 63, tid >> 6);
  if (tid < 16) blur_run(64 + (tid & 3), tid >> 2);
  __syncthreads();

  auto sob_run = [&](int col, int q) {
    const int y0  = (q < 2) ? q * 5 : 10 + (q - 2) * 4;
    const int len = (q < 2) ? 5 : 4;
    const int ix = bx0 - 1 + col;
    const bool colok = (ix >= 0 && ix < 512);
    float wn[3][3];
#pragma unroll
    for (int r = 0; r < 2; ++r)
#pragma unroll
      for (int c = 0; c < 3; ++c)
        wn[r][c] = s_blur[(y0 + r) * 68 + col + c];
#pragma unroll
    for (int y = 0; y < 5; ++y) {
      if (y < len) {
        const int pin = (y + 2) % 3;
#pragma unroll
        for (int c = 0; c < 3; ++c)
          wn[pin][c] = s_blur[(y0 + y + 2) * 68 + col + c];
        const int r0 = y % 3, r1 = (y + 1) % 3, r2 = (y + 2) % 3;
        double b00 = (double)wn[r0][0], b01 = (double)wn[r0][1], b02 = (double)wn[r0][2];
        double b10 = (double)wn[r1][0],                          b12 = (double)wn[r1][2];
        double b20 = (double)wn[r2][0], b21 = (double)wn[r2][1], b22 = (double)wn[r2][2];
        float gxf = (float)(((b02 - b00) + 2.0 * (b12 - b10)) + (b22 - b20));
        float gyf = (float)(((b20 - b00) + 2.0 * (b21 - b01)) + (b22 - b02));
        int iy = by0 - 1 + y0 + y;
        float mval = 0.0f;
        if (colok && iy >= 0 && iy < 512)
          mval = __fsqrt_rn(__fadd_rn(__fmul_rn(gxf, gxf), __fmul_rn(gyf, gyf)));
        s_mag[(y0 + y) * 66 + col] = mval;
        s_sec[(y0 + y) * 66 + col] = (unsigned char)sectorf(gxf, gyf);
      }
    }
  };
  sob_run(tid & 63, tid >> 6);
  if (tid < 8) sob_run(64 + (tid & 1), tid >> 1);
  __syncthreads();

  {
    const int col = tid & 63, q = tid >> 6;
    const int y0 = q * 4;
    float mw[3][3];
#pragma unroll
    for (int r = 0; r < 2; ++r)
#pragma unroll
      for (int c = 0; c < 3; ++c)
        mw[r][c] = s_mag[(y0 + r) * 66 + col + c];
#pragma unroll
    for (int y = 0; y < 4; ++y) {
      const int pin = (y + 2) % 3;
#pragma unroll
      for (int c = 0; c < 3; ++c)
        mw[pin][c] = s_mag[(y0 + y + 2) * 66 + col + c];
      const int r0 = y % 3, r1 = (y + 1) % 3, r2 = (y + 2) % 3;
      int sec = s_sec[(y0 + y + 1) * 66 + (col + 1)];
      float m = mw[r1][1];
      bool z;
      if (sec == 0)      z = (m >= mw[r1][0]) && (m >= mw[r1][2]);
      else if (sec == 1) z = (m >= mw[r2][0]) && (m >= mw[r0][2]);
      else if (sec == 2) z = (m >= mw[r0][1]) && (m >= mw[r2][1]);
      else               z = (m >= mw[r0][0]) && (m >= mw[r2][2]);
      outp[(size_t)(by0 + y0 + y) * 512 + (bx0 + col)] = z ? 0.998f : 0.002f;
    }
  }
}

// ---------------- interior path: vector LDS + fused ph3/4 ----------------
__device__ __forceinline__ void canny_tile_fast(
    const float* __restrict__ base, float* __restrict__ outp,
    int bx0, int by0, float* s_gray /*24x(76)*/, float* s_blur /*20x(76)*/,
    const double* w64, int tid) {
  const size_t plane = (size_t)512 * 512;

  // Phase 1: gray 24 rows x 72 cols (stride 76), float4 loads, b128 writes.
  for (int t = tid; t < 24 * 18; t += NT) {
    int row = t / 18, c4 = (t - row * 18) * 4;
    size_t idx = (size_t)(by0 - 4 + row) * 512 + (bx0 - 4 + c4);
    float4 r = *(const float4*)(base + idx);
    float4 g = *(const float4*)(base + idx + plane);
    float4 b = *(const float4*)(base + idx + 2 * plane);
    float4 o;
    o.x = grayf(r.x, g.x, b.x);
    o.y = grayf(r.y, g.y, b.y);
    o.z = grayf(r.z, g.z, b.z);
    o.w = grayf(r.w, g.w, b.w);
    *(float4*)(s_gray + row * 76 + c4) = o;
  }
  __syncthreads();

  // Phase 2: blur (20 rows x 68 cols region, stride 76). 17 col-groups x 5
  // row-runs of 4. Per row-step: 2 x ds_read_b128, 25 f64 FMA/px (verbatim
  // row-major chain), 1 x ds_write_b128.
  if (tid < 85) {
    const int k = tid / 5, q = tid - 5 * (tid / 5);
    const int r0 = q * 4;  // blur local rows r0..r0+3
    float g[5][8];
#pragma unroll
    for (int i = 0; i < 4; ++i) {
      float4 lo = *(const float4*)(s_gray + (r0 + i) * 76 + 4 * k);
      float4 hi = *(const float4*)(s_gray + (r0 + i) * 76 + 4 * k + 4);
      g[i][0] = lo.x; g[i][1] = lo.y; g[i][2] = lo.z; g[i][3] = lo.w;
      g[i][4] = hi.x; g[i][5] = hi.y; g[i][6] = hi.z; g[i][7] = hi.w;
    }
#pragma unroll
    for (int y = 0; y < 4; ++y) {
      const int pin = (y + 4) % 5;
      float4 lo = *(const float4*)(s_gray + (r0 + y + 4) * 76 + 4 * k);
      float4 hi = *(const float4*)(s_gray + (r0 + y + 4) * 76 + 4 * k + 4);
      g[pin][0] = lo.x; g[pin][1] = lo.y; g[pin][2] = lo.z; g[pin][3] = lo.w;
      g[pin][4] = hi.x; g[pin][5] = hi.y; g[pin][6] = hi.z; g[pin][7] = hi.w;
      float res[4];
#pragma unroll
      for (int t = 0; t < 4; ++t) {
        double acc = 0.0;
#pragma unroll
        for (int m = 0; m < 5; ++m) {
          const int s = (y + m) % 5;
#pragma unroll
          for (int c = 0; c < 5; ++c)
            acc = __builtin_fma(w64[m * 5 + c], (double)g[s][t + c], acc);
        }
        res[t] = (float)acc;
      }
      *(float4*)(s_blur + (r0 + y) * 76 + 4 * k) =
          make_float4(res[0], res[1], res[2], res[3]);
    }
  }
  __syncthreads();

  // Phase 3+4 fused: one wave; each thread owns a 4x4 output block.
  // Streams 8 blur rows (2 x b128 each), computes 6x6 mag + 4x4 sector in
  // registers, NMS + global_store_dwordx4. No LDS round-trip, no barrier.
  if (tid < 64) {
    const int gi = tid & 15, q = tid >> 4;
    const int c0 = 4 * gi;  // out local cols c0..c0+3
    const int r0 = 4 * q;   // out local rows r0..r0+3
    float B[3][8];
    float M[3][6];
    int sec[4][4];
#pragma unroll
    for (int d = 0; d < 2; ++d) {
      float4 lo = *(const float4*)(s_blur + (r0 + d) * 76 + c0);
      float4 hi = *(const float4*)(s_blur + (r0 + d) * 76 + c0 + 4);
      B[d][0] = lo.x; B[d][1] = lo.y; B[d][2] = lo.z; B[d][3] = lo.w;
      B[d][4] = hi.x; B[d][5] = hi.y; B[d][6] = hi.z; B[d][7] = hi.w;
    }
#pragma unroll
    for (int i = 0; i < 6; ++i) {
      const int pin = (i + 2) % 3;
      float4 lo = *(const float4*)(s_blur + (r0 + i + 2) * 76 + c0);
      float4 hi = *(const float4*)(s_blur + (r0 + i + 2) * 76 + c0 + 4);
      B[pin][0] = lo.x; B[pin][1] = lo.y; B[pin][2] = lo.z; B[pin][3] = lo.w;
      B[pin][4] = hi.x; B[pin][5] = hi.y; B[pin][6] = hi.z; B[pin][7] = hi.w;
      const int top = i % 3, mid = (i + 1) % 3, bot = (i + 2) % 3;
#pragma unroll
      for (int t = 0; t < 6; ++t) {
        double b00 = (double)B[top][t], b01 = (double)B[top][t + 1], b02 = (double)B[top][t + 2];
        double b10 = (double)B[mid][t],                              b12 = (double)B[mid][t + 2];
        double b20 = (double)B[bot][t], b21 = (double)B[bot][t + 1], b22 = (double)B[bot][t + 2];
        float gxf = (float)(((b02 - b00) + 2.0 * (b12 - b10)) + (b22 - b20));
        float gyf = (float)(((b20 - b00) + 2.0 * (b21 - b01)) + (b22 - b02));
        M[i % 3][t] = __fsqrt_rn(__fadd_rn(__fmul_rn(gxf, gxf), __fmul_rn(gyf, gyf)));
        if (i >= 1 && i <= 4 && t >= 1 && t <= 4)
          sec[i - 1][t - 1] = sectorf(gxf, gyf);
      }
      if (i >= 2) {
        const int j = i - 2;
        const int tp = j % 3, md = (j + 1) % 3, bt = (j + 2) % 3;
        float res[4];
#pragma unroll
        for (int u = 0; u < 4; ++u) {
          const int t = u + 1;
          float m = M[md][t];
          int s = sec[j][u];
          bool z;
          if (s == 0)      z = (m >= M[md][t - 1]) && (m >= M[md][t + 1]);
          else if (s == 1) z = (m >= M[bt][t - 1]) && (m >= M[tp][t + 1]);
          else if (s == 2) z = (m >= M[tp][t]) && (m >= M[bt][t]);
          else             z = (m >= M[tp][t - 1]) && (m >= M[bt][t + 1]);
          res[u] = z ? 0.998f : 0.002f;
        }
        *(float4*)(outp + (size_t)(by0 + r0 + j) * 512 + (bx0 + c0)) =
            make_float4(res[0], res[1], res[2], res[3]);
      }
    }
  }
}

__global__ __launch_bounds__(NT, 6) void canny_v6(const float* __restrict__ x,
                                                  float* __restrict__ out) {
  __shared__ __align__(16) float s_u[1824];      // interior gray 24x76 / border gray+mag+sec
  __shared__ __align__(16) float s_blur[1520];   // interior blur 20x76 / border blur 20x68

  const int tid = threadIdx.x;
  const int bid = blockIdx.x;
  const int txi = bid & 7, tyi = (bid >> 3) & 31;
  const int bx0 = txi * 64;
  const int by0 = tyi * 16;
  const int n   = bid >> 8;
  const float* base = x + (size_t)n * 3 * 512 * 512;
  float* outp = out + (size_t)n * 512 * 512;

  // weights: CR f32 exps, numpy-pairwise f32 sum, f32 divide (verbatim;
  // constant-folds at compile time)
  const float E05 = (float)exp(-0.5);
  const float E1  = (float)exp(-1.0);
  const float E2  = (float)exp(-2.0);
  const float E25 = (float)exp(-2.5);
  const float E4  = (float)exp(-4.0);
  const float a25[25] = {E4,E25,E2,E25,E4,  E25,E1,E05,E1,E25,
                         E2,E05,1.0f,E05,E2, E25,E1,E05,E1,E25,
                         E4,E25,E2,E25,E4};
  float r8[8];
#pragma unroll
  for (int j = 0; j < 8; ++j)
    r8[j] = __fadd_rn(__fadd_rn(a25[j], a25[j + 8]), a25[j + 16]);
  float S32 = __fadd_rn(__fadd_rn(__fadd_rn(r8[0], r8[1]), __fadd_rn(r8[2], r8[3])),
                        __fadd_rn(__fadd_rn(r8[4], r8[5]), __fadd_rn(r8[6], r8[7])));
  S32 = __fadd_rn(S32, a25[24]);
  double w64[25];
#pragma unroll
  for (int t = 0; t < 25; ++t) w64[t] = (double)__fdiv_rn(a25[t], S32);

  const bool border = (txi == 0) | (txi == 7) | (tyi == 0) | (tyi == 31);
  if (border) {
    float* s_gray = s_u;
    float* s_mag  = s_u;
    unsigned char* s_sec = (unsigned char*)(s_u + 1188);
    canny_tile_border(base, outp, bx0, by0, s_gray, s_blur, s_mag, s_sec, w64, tid);
  } else {
    canny_tile_fast(base, outp, bx0, by0, s_u, s_blur, w64, tid);
  }
}

extern "C" void kernel_launch(void* const* d_in, const int* in_sizes, int n_in,
                              void* d_out, int out_size, void* d_ws, size_t ws_size,
                              hipStream_t stream) {
  const float* x = (const float*)d_in[0];
  float* out = (float*)d_out;
  hipLaunchKernelGGL(canny_v6, dim3(8192), dim3(NT), 0, stream, x, out);
}

// Round 12
// 60.635 us; speedup vs baseline: 2.2098x; 2.2098x over previous
//
#include <hip/hip_runtime.h>
#include <math.h>

// Canny NMS mask, bit-exact vs the validated round-5 pipeline.
// v7 = v5 (58.5us known-good) + interior-only fused phase 3+4:
//   - all 256 threads active: wave w -> out rows 4w..4w+3, lane l -> out col l
//   - mag kept in 3-row register history; left/right neighbors via
//     __shfl_up/__shfl_down(1); edge mag cols 0/65 by lanes 0/63 (masked,
//     one extra blur column each)
//   - removes mag/sec LDS round-trip + 3rd barrier; sobel count 6rows/4out
//   - all register-array indices compile-time (offset-from-rbase % 3 under
//     full unroll) -- no scratch (round-11 lesson)
// Border tiles run the v5 path verbatim. Arithmetic chains are IDENTICAL
// to the validated pipeline on every path.

#define NT 256

__device__ __forceinline__ float grayf(float r, float g, float b) {
  return __fadd_rn(__fadd_rn(__fmul_rn(0.299f, r), __fmul_rn(0.587f, g)),
                   __fmul_rn(0.114f, b));
}

// sector: f32 slope test w/ guard band; in-band -> verbatim atan2f chain
__device__ __forceinline__ int sectorf(float gxf, float gyf) {
  const float Tnf = 0.41421356237309504880f;
  const float BETAf = 1e-4f;
  const float RAD2DEG = (float)(180.0 / 3.14159265358979323846);
  float uf = (gyf < 0.0f) ? -gxf : gxf;
  float vf = fabsf(gyf);
  float au = fabsf(uf);
  float p = au * Tnf, qq = vf * Tnf;
  int sec;
  if (uf > 0.0f)      sec = (vf < p) ? 0 : (uf > qq) ? 1 : 2;
  else if (uf < 0.0f) sec = (uf > -qq) ? 2 : (vf > p) ? 3 : 0;
  else                sec = (vf > 0.0f) ? 2 : 0;
  bool slow = (fabsf(vf - p) <= p * BETAf) || (fabsf(au - qq) <= qq * BETAf);
  if (slow) {
    float ang = __fmul_rn(atan2f(gyf, gxf), RAD2DEG);
    if (ang < 0.0f) ang = __fadd_rn(ang, 180.0f);
    sec = (ang < 22.5f) ? 0 : (ang < 67.5f) ? 1
        : (ang < 112.5f) ? 2 : (ang < 157.5f) ? 3 : 0;
  }
  return sec;
}

// ---------------- border path: v5 verbatim (scalar, masked) ----------------
__device__ __forceinline__ void canny_tile_border(
    const float* __restrict__ base, float* __restrict__ outp,
    int bx0, int by0, float* s_gray, float* s_blur, float* s_mag,
    unsigned char* s_sec, const double* w64, int tid) {
  const size_t plane = (size_t)512 * 512;

  for (int i = tid; i < 24 * 72; i += NT) {
    int ly = i / 72, lx = i - ly * 72;
    int gy = by0 - 4 + ly, gx = bx0 - 4 + lx;
    float val = 0.0f;
    if (gy >= 0 && gy < 512 && gx >= 0 && gx < 512) {
      size_t idx = (size_t)gy * 512 + gx;
      val = grayf(base[idx], base[idx + plane], base[idx + 2 * plane]);
    }
    s_gray[i] = val;
  }
  __syncthreads();

  auto blur_run = [&](int col, int q) {
    const int y0 = q * 5;
    const int ix = bx0 - 2 + col;
    const bool colok = (ix >= 0 && ix < 512);
    float win[5][5];
#pragma unroll
    for (int r = 0; r < 4; ++r)
#pragma unroll
      for (int c = 0; c < 5; ++c)
        win[r][c] = s_gray[(y0 + r) * 72 + col + c];
#pragma unroll
    for (int y = 0; y < 5; ++y) {
      const int pin = (y + 4) % 5;
#pragma unroll
      for (int c = 0; c < 5; ++c)
        win[pin][c] = s_gray[(y0 + y + 4) * 72 + col + c];
      double acc = 0.0;
#pragma unroll
      for (int r = 0; r < 5; ++r) {
        const int ph = (y + r) % 5;
#pragma unroll
        for (int c = 0; c < 5; ++c)
          acc = __builtin_fma(w64[r * 5 + c], (double)win[ph][c], acc);
      }
      int iy = by0 - 2 + y0 + y;
      s_blur[(y0 + y) * 68 + col] =
          (colok && iy >= 0 && iy < 512) ? (float)acc : 0.0f;
    }
  };
  blur_run(tid & 63, tid >> 6);
  if (tid < 16) blur_run(64 + (tid & 3), tid >> 2);
  __syncthreads();

  auto sob_run = [&](int col, int q) {
    const int y0  = (q < 2) ? q * 5 : 10 + (q - 2) * 4;
    const int len = (q < 2) ? 5 : 4;
    const int ix = bx0 - 1 + col;
    const bool colok = (ix >= 0 && ix < 512);
    float wn[3][3];
#pragma unroll
    for (int r = 0; r < 2; ++r)
#pragma unroll
      for (int c = 0; c < 3; ++c)
        wn[r][c] = s_blur[(y0 + r) * 68 + col + c];
#pragma unroll
    for (int y = 0; y < 5; ++y) {
      if (y < len) {
        const int pin = (y + 2) % 3;
#pragma unroll
        for (int c = 0; c < 3; ++c)
          wn[pin][c] = s_blur[(y0 + y + 2) * 68 + col + c];
        const int r0 = y % 3, r1 = (y + 1) % 3, r2 = (y + 2) % 3;
        double b00 = (double)wn[r0][0], b01 = (double)wn[r0][1], b02 = (double)wn[r0][2];
        double b10 = (double)wn[r1][0],                          b12 = (double)wn[r1][2];
        double b20 = (double)wn[r2][0], b21 = (double)wn[r2][1], b22 = (double)wn[r2][2];
        float gxf = (float)(((b02 - b00) + 2.0 * (b12 - b10)) + (b22 - b20));
        float gyf = (float)(((b20 - b00) + 2.0 * (b21 - b01)) + (b22 - b02));
        int iy = by0 - 1 + y0 + y;
        float mval = 0.0f;
        if (colok && iy >= 0 && iy < 512)
          mval = __fsqrt_rn(__fadd_rn(__fmul_rn(gxf, gxf), __fmul_rn(gyf, gyf)));
        s_mag[(y0 + y) * 66 + col] = mval;
        s_sec[(y0 + y) * 66 + col] = (unsigned char)sectorf(gxf, gyf);
      }
    }
  };
  sob_run(tid & 63, tid >> 6);
  if (tid < 8) sob_run(64 + (tid & 1), tid >> 1);
  __syncthreads();

  {
    const int col = tid & 63, q = tid >> 6;
    const int y0 = q * 4;
    float mw[3][3];
#pragma unroll
    for (int r = 0; r < 2; ++r)
#pragma unroll
      for (int c = 0; c < 3; ++c)
        mw[r][c] = s_mag[(y0 + r) * 66 + col + c];
#pragma unroll
    for (int y = 0; y < 4; ++y) {
      const int pin = (y + 2) % 3;
#pragma unroll
      for (int c = 0; c < 3; ++c)
        mw[pin][c] = s_mag[(y0 + y + 2) * 66 + col + c];
      const int r0 = y % 3, r1 = (y + 1) % 3, r2 = (y + 2) % 3;
      int sec = s_sec[(y0 + y + 1) * 66 + (col + 1)];
      float m = mw[r1][1];
      bool z;
      if (sec == 0)      z = (m >= mw[r1][0]) && (m >= mw[r1][2]);
      else if (sec == 1) z = (m >= mw[r2][0]) && (m >= mw[r0][2]);
      else if (sec == 2) z = (m >= mw[r0][1]) && (m >= mw[r2][1]);
      else               z = (m >= mw[r0][0]) && (m >= mw[r2][2]);
      outp[(size_t)(by0 + y0 + y) * 512 + (bx0 + col)] = z ? 0.998f : 0.002f;
    }
  }
}

// ------------- interior path: v5 P1/P2 + register-fused P3/P4 -------------
__device__ __forceinline__ void canny_tile_fast(
    const float* __restrict__ base, float* __restrict__ outp,
    int bx0, int by0, float* s_gray, float* s_blur, const double* w64,
    int tid) {
  const size_t plane = (size_t)512 * 512;

  // Phase 1: gray 24x72, float4 loads + b128 LDS writes (stride 72, 16B ok)
  for (int t = tid; t < 24 * 18; t += NT) {
    int row = t / 18, c4 = (t - row * 18) * 4;
    size_t idx = (size_t)(by0 - 4 + row) * 512 + (bx0 - 4 + c4);
    float4 r = *(const float4*)(base + idx);
    float4 g = *(const float4*)(base + idx + plane);
    float4 b = *(const float4*)(base + idx + 2 * plane);
    float4 o;
    o.x = grayf(r.x, g.x, b.x);
    o.y = grayf(r.y, g.y, b.y);
    o.z = grayf(r.z, g.z, b.z);
    o.w = grayf(r.w, g.w, b.w);
    *(float4*)(s_gray + row * 72 + c4) = o;
  }
  __syncthreads();

  // Phase 2: blur 20x68 (v5 verbatim, no masks needed: interior)
  auto blur_run = [&](int col, int q) {
    const int y0 = q * 5;
    float win[5][5];
#pragma unroll
    for (int r = 0; r < 4; ++r)
#pragma unroll
      for (int c = 0; c < 5; ++c)
        win[r][c] = s_gray[(y0 + r) * 72 + col + c];
#pragma unroll
    for (int y = 0; y < 5; ++y) {
      const int pin = (y + 4) % 5;
#pragma unroll
      for (int c = 0; c < 5; ++c)
        win[pin][c] = s_gray[(y0 + y + 4) * 72 + col + c];
      double acc = 0.0;
#pragma unroll
      for (int r = 0; r < 5; ++r) {
        const int ph = (y + r) % 5;
#pragma unroll
        for (int c = 0; c < 5; ++c)
          acc = __builtin_fma(w64[r * 5 + c], (double)win[ph][c], acc);
      }
      s_blur[(y0 + y) * 68 + col] = (float)acc;
    }
  };
  blur_run(tid & 63, tid >> 6);
  if (tid < 16) blur_run(64 + (tid & 3), tid >> 2);
  __syncthreads();

  // Fused P3+4: wave wv -> out rows 4wv..4wv+3; lane l -> out col l.
  // Lane's center mag col = l+1 (blur cols l+1..l+3). Neighbors via shfl.
  // Edge mag cols 0 / 65: lanes 0 / 63 read one extra blur col (0 / 67).
  {
    const int lane  = tid & 63;
    const int wv    = tid >> 6;
    const int rbase = 4 * wv;           // first of 6 mag rows
    const bool edge = (lane == 0) || (lane == 63);
    const int  ecol = (lane == 0) ? 0 : 67;   // extra blur col
    float bC[3][3];                     // blur rows (j%3) x cols l+1..l+3
    float bE[3];                        // extra blur col history
    float MC[3], ML[3], MR[3];
    int secPrev = 0;
#pragma unroll
    for (int j = 0; j < 2; ++j) {
      const int br = rbase + j;
#pragma unroll
      for (int c = 0; c < 3; ++c)
        bC[j][c] = s_blur[br * 68 + lane + 1 + c];
      if (edge) bE[j] = s_blur[br * 68 + ecol];
    }
#pragma unroll
    for (int s = 0; s < 6; ++s) {
      const int jn = (s + 2) % 3;
      const int br = rbase + s + 2;
#pragma unroll
      for (int c = 0; c < 3; ++c)
        bC[jn][c] = s_blur[br * 68 + lane + 1 + c];
      if (edge) bE[jn] = s_blur[br * 68 + ecol];

      const int t0 = s % 3, t1 = (s + 1) % 3, t2 = jn;
      double b00 = (double)bC[t0][0], b01 = (double)bC[t0][1], b02 = (double)bC[t0][2];
      double b10 = (double)bC[t1][0],                          b12 = (double)bC[t1][2];
      double b20 = (double)bC[t2][0], b21 = (double)bC[t2][1], b22 = (double)bC[t2][2];
      float gxf = (float)(((b02 - b00) + 2.0 * (b12 - b10)) + (b22 - b20));
      float gyf = (float)(((b20 - b00) + 2.0 * (b21 - b01)) + (b22 - b02));
      float mC = __fsqrt_rn(__fadd_rn(__fmul_rn(gxf, gxf), __fmul_rn(gyf, gyf)));

      float mE = 0.0f;
      if (edge) {
        // lane 0: window cols {bE, bC0, bC1} (blur 0,1,2)
        // lane 63: window cols {bC1, bC2, bE} (blur 65,66,67)
        float w00, w01, w02, w10, w11, w12, w20, w21, w22;
        if (lane == 0) {
          w00 = bE[t0]; w01 = bC[t0][0]; w02 = bC[t0][1];
          w10 = bE[t1]; w11 = bC[t1][0]; w12 = bC[t1][1];
          w20 = bE[t2]; w21 = bC[t2][0]; w22 = bC[t2][1];
        } else {
          w00 = bC[t0][1]; w01 = bC[t0][2]; w02 = bE[t0];
          w10 = bC[t1][1]; w11 = bC[t1][2]; w12 = bE[t1];
          w20 = bC[t2][1]; w21 = bC[t2][2]; w22 = bE[t2];
        }
        double e00 = (double)w00, e01 = (double)w01, e02 = (double)w02;
        double e10 = (double)w10,                    e12 = (double)w12;
        double e20 = (double)w20, e21 = (double)w21, e22 = (double)w22;
        float egx = (float)(((e02 - e00) + 2.0 * (e12 - e10)) + (e22 - e20));
        float egy = (float)(((e20 - e00) + 2.0 * (e21 - e01)) + (e22 - e02));
        mE = __fsqrt_rn(__fadd_rn(__fmul_rn(egx, egx), __fmul_rn(egy, egy)));
        (void)w11;
      }
      float mL = __shfl_up(mC, 1);
      float mR = __shfl_down(mC, 1);
      if (lane == 0)  mL = mE;
      if (lane == 63) mR = mE;
      const int ms = s % 3;
      MC[ms] = mC; ML[ms] = mL; MR[ms] = mR;

      if (s >= 2) {  // NMS for out row rbase+s-2 (mag rows s-2,s-1,s)
        const int top = (s - 2) % 3, mid = (s - 1) % 3, bot = ms;
        float m = MC[mid];
        bool z;
        if (secPrev == 0)      z = (m >= ML[mid]) && (m >= MR[mid]);
        else if (secPrev == 1) z = (m >= ML[bot]) && (m >= MR[top]);
        else if (secPrev == 2) z = (m >= MC[top]) && (m >= MC[bot]);
        else                   z = (m >= ML[top]) && (m >= MR[bot]);
        outp[(size_t)(by0 + rbase + s - 2) * 512 + (bx0 + lane)] =
            z ? 0.998f : 0.002f;
      }
      if (s >= 1 && s <= 4) secPrev = sectorf(gxf, gyf);
    }
  }
}

__global__ __launch_bounds__(NT, 8) void canny_v7(const float* __restrict__ x,
                                                  float* __restrict__ out) {
  __shared__ __align__(16) float s_u[1728];     // gray 24x72 / border mag+sec
  __shared__ __align__(16) float s_blur[1360];  // blur 20x68

  const int tid = threadIdx.x;
  const int bid = blockIdx.x;
  const int txi = bid & 7, tyi = (bid >> 3) & 31;
  const int bx0 = txi * 64;
  const int by0 = tyi * 16;
  const int n   = bid >> 8;
  const float* base = x + (size_t)n * 3 * 512 * 512;
  float* outp = out + (size_t)n * 512 * 512;

  // weights: CR f32 exps, numpy-pairwise f32 sum, f32 divide (verbatim;
  // constant-folds at compile time)
  const float E05 = (float)exp(-0.5);
  const float E1  = (float)exp(-1.0);
  const float E2  = (float)exp(-2.0);
  const float E25 = (float)exp(-2.5);
  const float E4  = (float)exp(-4.0);
  const float a25[25] = {E4,E25,E2,E25,E4,  E25,E1,E05,E1,E25,
                         E2,E05,1.0f,E05,E2, E25,E1,E05,E1,E25,
                         E4,E25,E2,E25,E4};
  float r8[8];
#pragma unroll
  for (int j = 0; j < 8; ++j)
    r8[j] = __fadd_rn(__fadd_rn(a25[j], a25[j + 8]), a25[j + 16]);
  float S32 = __fadd_rn(__fadd_rn(__fadd_rn(r8[0], r8[1]), __fadd_rn(r8[2], r8[3])),
                        __fadd_rn(__fadd_rn(r8[4], r8[5]), __fadd_rn(r8[6], r8[7])));
  S32 = __fadd_rn(S32, a25[24]);
  double w64[25];
#pragma unroll
  for (int t = 0; t < 25; ++t) w64[t] = (double)__fdiv_rn(a25[t], S32);

  const bool border = (txi == 0) | (txi == 7) | (tyi == 0) | (tyi == 31);
  if (border) {
    float* s_gray = s_u;
    float* s_mag  = s_u;
    unsigned char* s_sec = (unsigned char*)(s_u + 1188);
    canny_tile_border(base, outp, bx0, by0, s_gray, s_blur, s_mag, s_sec, w64, tid);
  } else {
    canny_tile_fast(base, outp, bx0, by0, s_u, s_blur, w64, tid);
  }
}

extern "C" void kernel_launch(void* const* d_in, const int* in_sizes, int n_in,
                              void* d_out, int out_size, void* d_ws, size_t ws_size,
                              hipStream_t stream) {
  const float* x = (const float*)d_in[0];
  float* out = (float*)d_out;
  hipLaunchKernelGGL(canny_v7, dim3(8192), dim3(NT), 0, stream, x, out);
}